// Round 7
// baseline (170.746 us; speedup 1.0000x reference)
//
#include <hip/hip_runtime.h>

// MHSA fwd MFMA bf16: B=8, N=1024, D=1024, H=16, DK=64. fp32 in/out, bf16 compute.
// Round 7: GEMMs -> deep-pipeline template, per-wave 128-row output for GEMM1.
//   GEMM1: BM=256 BN=192 BK=32, grid 16x32=512 (2 exact rounds), 8 waves 2Mx4N,
//          per-wave 128x48 (8 m-frags x 3 n-frags), 4-buf LDS, 3-tile lookahead,
//          tile-top vmcnt(8).
//   GEMM2: BM=128 BN=256 BK=32, grid 4x64=256 (1 exact round), per-wave 64x64,
//          4-buf, vmcnt(6).
// Attention unchanged from round 3.

typedef __attribute__((ext_vector_type(8))) short bf16x8;
typedef __attribute__((ext_vector_type(4))) float f32x4;

#define GLOAD_LDS16(gp, lp)                                                              \
  __builtin_amdgcn_global_load_lds((const __attribute__((address_space(1))) void*)(gp),  \
                                   (__attribute__((address_space(3))) void*)(lp), 16, 0, 0)

__device__ __forceinline__ unsigned short f2bf(float f) {
  unsigned int u = __float_as_uint(f);
  u += 0x7fffu + ((u >> 16) & 1u);          // RNE
  return (unsigned short)(u >> 16);
}

// ---------------------------------------------------------------------------
__global__ __launch_bounds__(256) void cast_f32_to_bf16(
    const float* __restrict__ in, unsigned short* __restrict__ out, int n4) {
  int stride = gridDim.x * blockDim.x;
  for (int i = blockIdx.x * blockDim.x + threadIdx.x; i < n4; i += stride) {
    float4 v = reinterpret_cast<const float4*>(in)[i];
    ushort4 o;
    o.x = f2bf(v.x); o.y = f2bf(v.y); o.z = f2bf(v.z); o.w = f2bf(v.w);
    reinterpret_cast<ushort4*>(out)[i] = o;
  }
}

// W [R][C] f32 -> Wt [C][R] bf16
__global__ __launch_bounds__(256) void transpose_cast(
    const float* __restrict__ W, unsigned short* __restrict__ Wt, int R, int C) {
  __shared__ float tile[32][33];
  int tx = threadIdx.x & 31, ty = threadIdx.x >> 5;
  int c0 = blockIdx.x * 32, r0 = blockIdx.y * 32;
  #pragma unroll
  for (int i = 0; i < 4; i++) {
    int r = r0 + ty + i * 8;
    tile[ty + i * 8][tx] = W[(size_t)r * C + c0 + tx];
  }
  __syncthreads();
  #pragma unroll
  for (int i = 0; i < 4; i++) {
    int c = c0 + ty + i * 8;
    Wt[(size_t)c * R + r0 + tx] = f2bf(tile[tx][ty + i * 8]);
  }
}

// ---------------------------------------------------------------------------
// Deep-pipelined GEMM. A [8192][1024] bf16, Bt [N][1024] bf16 (B^T), K=1024.
// BK=32 (32 K-tiles), 512 thr = 8 waves (2M x 4N). 4 LDS buffers, tile kt+3
// staged during tile kt (A-part in phase 0, B-part in phase 1), tile-top
// counted vmcnt (2 tiles in flight), 2 phases x (MF/2 x NF) MFMA per tile.
// MODE 0: BM=256 BN=192; qkv scatter (Q pre-scaled 0.125, V transposed).
// MODE 1: BM=128 BN=256; f32 out + bias.
// ---------------------------------------------------------------------------
template <int MODE>
__global__ __launch_bounds__(512, 2) void gemm_dp(
    const unsigned short* __restrict__ Aop, const unsigned short* __restrict__ Bop,
    const float* __restrict__ bias, unsigned short* __restrict__ qkv_out,
    float* __restrict__ Cout) {
  constexpr int BM = (MODE == 0) ? 256 : 128;
  constexpr int BN = (MODE == 0) ? 192 : 256;
  constexpr int MF = BM / 32;          // m-frags per wave (8 / 4)
  constexpr int NF = BN / 64;          // n-frags per wave (3 / 4)
  constexpr int WNSZ = BN / 4;         // per-wave col span (48 / 64)
  constexpr int NA = BM / 128;         // A gloads per tile (2 / 1)

  __shared__ __align__(16) unsigned short As[4][BM * 32];
  __shared__ __align__(16) unsigned short Bs[4][BN * 32];

  const int t = threadIdx.x;
  const int lane = t & 63, wid = t >> 6;
  const int lr = lane & 15, g = lane >> 4;
  const int wm = wid >> 2, wn = wid & 3;

  // XCD-aware swizzle (nwg % 8 == 0 for both modes)
  const int nwg = gridDim.x * gridDim.y;
  const int id = blockIdx.x + gridDim.x * blockIdx.y;
  const int sw = (id & 7) * (nwg >> 3) + (id >> 3);
  const int bx = sw % gridDim.x, by = sw / gridDim.x;
  const int row0 = by * BM, col0 = bx * BN;

  const int srow = t >> 2;                       // 0..127 (64B rows)
  const int sch  = (t & 3) ^ ((srow >> 1) & 3);  // source pre-swizzle chunk

  auto stageA = [&](int buf, int kt2) {
    #pragma unroll
    for (int j = 0; j < NA; j++) {
      GLOAD_LDS16(Aop + (size_t)(row0 + j * 128 + srow) * 1024 + kt2 * 32 + sch * 8,
                  (char*)&As[buf][0] + j * 8192 + t * 16);
    }
  };
  auto stageB = [&](int buf, int kt2) {
    #pragma unroll
    for (int j = 0; j < 2; j++) {
      int rb = (MODE == 0) ? j * 64 : j * 128;   // MODE0: overlapping (idempotent)
      GLOAD_LDS16(Bop + (size_t)(col0 + rb + srow) * 1024 + kt2 * 32 + sch * 8,
                  (char*)&Bs[buf][0] + rb * 64 + t * 16);
    }
  };
  auto rdA = [&](int buf, int m) -> bf16x8 {
    int r = wm * (BM / 2) + m * 16 + lr;
    return *(const bf16x8*)((const char*)&As[buf][0] + r * 64 +
                            ((g ^ ((r >> 1) & 3)) * 16));
  };
  auto rdB = [&](int buf, int n) -> bf16x8 {
    int r = wn * WNSZ + n * 16 + lr;
    return *(const bf16x8*)((const char*)&Bs[buf][0] + r * 64 +
                            ((g ^ ((r >> 1) & 3)) * 16));
  };

  f32x4 acc[MF][NF] = {};

  // prologue: stage tiles 0..2 (3 tiles in flight)
  stageA(0, 0); stageB(0, 0);
  stageA(1, 1); stageB(1, 1);
  stageA(2, 2); stageB(2, 2);

  for (int kt = 0; kt < 32; kt++) {
    const int buf = kt & 3;
    const int rem = 31 - kt;
    // tile-top counted wait: own tile landed, next 2 tiles stay in flight
    if (rem >= 2) {
      if constexpr (MODE == 0) asm volatile("s_waitcnt vmcnt(8)" ::: "memory");
      else                     asm volatile("s_waitcnt vmcnt(6)" ::: "memory");
    } else if (rem == 1) {
      if constexpr (MODE == 0) asm volatile("s_waitcnt vmcnt(4)" ::: "memory");
      else                     asm volatile("s_waitcnt vmcnt(3)" ::: "memory");
    } else {
      asm volatile("s_waitcnt vmcnt(0)" ::: "memory");
    }
    __builtin_amdgcn_s_barrier();

    bf16x8 bfr[NF], afr[MF / 2];

    // ---- phase 0: m-frags [0, MF/2) ----
    #pragma unroll
    for (int n = 0; n < NF; n++) bfr[n] = rdB(buf, n);
    #pragma unroll
    for (int m = 0; m < MF / 2; m++) afr[m] = rdA(buf, m);
    if (kt <= 28) stageA((kt + 3) & 3, kt + 3);
    __builtin_amdgcn_s_barrier();
    asm volatile("s_waitcnt lgkmcnt(0)" ::: "memory");
    __builtin_amdgcn_sched_barrier(0);
    __builtin_amdgcn_s_setprio(1);
    #pragma unroll
    for (int m = 0; m < MF / 2; m++)
      #pragma unroll
      for (int n = 0; n < NF; n++)
        acc[m][n] = __builtin_amdgcn_mfma_f32_16x16x32_bf16(afr[m], bfr[n], acc[m][n], 0, 0, 0);
    __builtin_amdgcn_s_setprio(0);
    __builtin_amdgcn_s_barrier();

    // ---- phase 1: m-frags [MF/2, MF) ----
    #pragma unroll
    for (int m = 0; m < MF / 2; m++) afr[m] = rdA(buf, MF / 2 + m);
    if (kt <= 28) stageB((kt + 3) & 3, kt + 3);
    __builtin_amdgcn_s_barrier();
    asm volatile("s_waitcnt lgkmcnt(0)" ::: "memory");
    __builtin_amdgcn_sched_barrier(0);
    __builtin_amdgcn_s_setprio(1);
    #pragma unroll
    for (int m = 0; m < MF / 2; m++)
      #pragma unroll
      for (int n = 0; n < NF; n++)
        acc[MF / 2 + m][n] =
            __builtin_amdgcn_mfma_f32_16x16x32_bf16(afr[m], bfr[n], acc[MF / 2 + m][n], 0, 0, 0);
    __builtin_amdgcn_s_setprio(0);
    __builtin_amdgcn_s_barrier();
  }

  // ---------------- epilogue ----------------
  #pragma unroll
  for (int m = 0; m < MF; m++) {
    const int row = row0 + wm * (BM / 2) + m * 16 + g * 4;
    #pragma unroll
    for (int n = 0; n < NF; n++) {
      const int col = col0 + wn * WNSZ + n * 16 + lr;
      if constexpr (MODE == 0) {
        const int which = col >> 10;           // per-frag (frag never straddles)
        const int cc = col & 1023, h = cc >> 6, dk = cc & 63;
        const int bb = row >> 10, nn = row & 1023;
        const float bv = bias[col];
        if (which == 2) {
          ushort4 w;
          w.x = f2bf(acc[m][n][0] + bv);
          w.y = f2bf(acc[m][n][1] + bv);
          w.z = f2bf(acc[m][n][2] + bv);
          w.w = f2bf(acc[m][n][3] + bv);
          size_t idx = ((size_t)2 << 23) + (((size_t)(bb * 16 + h)) << 16) +
                       (size_t)dk * 1024 + nn;
          *(ushort4*)(qkv_out + idx) = w;
        } else {
          const float sc = (which == 0) ? 0.125f : 1.0f;
          #pragma unroll
          for (int r = 0; r < 4; r++) {
            size_t idx = ((size_t)which << 23) +
                         (((size_t)((bb * 16 + h) * 1024 + nn + r)) << 6) + dk;
            qkv_out[idx] = f2bf((acc[m][n][r] + bv) * sc);
          }
        }
      } else {
        const float bv = bias[col];
        #pragma unroll
        for (int r = 0; r < 4; r++)
          Cout[(size_t)(row + r) * 1024 + col] = acc[m][n][r] + bv;
      }
    }
  }
}

// ---------------------------------------------------------------------------
// Attention (unchanged): 8 waves, QBLK=128, KVBLK=64, dbuf prefetch,
// V pre-transposed by GEMM1, setprio, XCD swizzle.
// ---------------------------------------------------------------------------
__global__ __launch_bounds__(512) void attn_mfma(
    const unsigned short* __restrict__ qkv, unsigned short* __restrict__ attn_out) {
  __shared__ __align__(16) unsigned short K_lds[2][64 * 64];   // [k][d] swz
  __shared__ __align__(16) unsigned short V_lds[2][64 * 64];   // [d][k] swz
  __shared__ __align__(16) unsigned short P_lds[128 * 64];     // [q][k] swz

  const int bid = ((blockIdx.x & 7) << 7) + (blockIdx.x >> 3);
  const int bh = bid >> 3, qt = bid & 7;
  const unsigned short* Qp = qkv + ((size_t)bh << 16);
  const unsigned short* Kp = qkv + (1u << 23) + ((size_t)bh << 16);
  const unsigned short* Vt = qkv + (2u << 23) + ((size_t)bh << 16);  // [dk][n]

  const int t = threadIdx.x;
  const int lane = t & 63, wid = t >> 6;
  const int lr = lane & 15, g = lane >> 4;

  bf16x8 qf[2];
  {
    int qrow = qt * 128 + wid * 16 + lr;
    qf[0] = *(const bf16x8*)(Qp + (size_t)qrow * 64 + g * 8);
    qf[1] = *(const bf16x8*)(Qp + (size_t)qrow * 64 + 32 + g * 8);
  }

  const int srow = t >> 3;
  const int sch  = (t & 7) ^ (srow & 7);
  const int so   = t * 16;

  auto stage = [&](int buf, int kt) {
    GLOAD_LDS16(Kp + (size_t)(kt * 64 + srow) * 64 + sch * 8, (char*)&K_lds[buf][0] + so);
    GLOAD_LDS16(Vt + (size_t)srow * 1024 + kt * 64 + sch * 8, (char*)&V_lds[buf][0] + so);
  };

  f32x4 o_acc[4] = {};
  float den[4] = {0.f, 0.f, 0.f, 0.f};

  stage(0, 0);
  __syncthreads();
  int buf = 0;
  for (int kt = 0; kt < 16; kt++) {
    if (kt + 1 < 16) stage(buf ^ 1, kt + 1);

    f32x4 s4[4] = {};
    __builtin_amdgcn_s_setprio(1);
    #pragma unroll
    for (int ks = 0; ks < 4; ks++) {
      int krow = ks * 16 + lr;
      #pragma unroll
      for (int c = 0; c < 2; c++) {
        bf16x8 kf = *(const bf16x8*)((char*)&K_lds[buf][0] + krow * 128 +
                                     ((c * 64 + g * 16) ^ ((krow & 7) << 4)));
        s4[ks] = __builtin_amdgcn_mfma_f32_16x16x32_bf16(qf[c], kf, s4[ks], 0, 0, 0);
      }
    }
    __builtin_amdgcn_s_setprio(0);

    #pragma unroll
    for (int ks = 0; ks < 4; ks++) {
      #pragma unroll
      for (int r = 0; r < 4; r++) {
        float e = __expf(s4[ks][r]);
        den[r] += e;
        int q = wid * 16 + g * 4 + r;
        *(unsigned short*)((char*)P_lds + q * 128 +
                           (((ks * 16 + lr) * 2) ^ ((q & 7) << 4))) = f2bf(e);
      }
    }

    bf16x8 pa[2];
    {
      int q = wid * 16 + lr;
      #pragma unroll
      for (int c = 0; c < 2; c++)
        pa[c] = *(const bf16x8*)((char*)P_lds + q * 128 +
                                 ((c * 64 + g * 16) ^ ((q & 7) << 4)));
    }
    __builtin_amdgcn_s_setprio(1);
    #pragma unroll
    for (int ds_ = 0; ds_ < 4; ds_++) {
      int drow = ds_ * 16 + lr;
      #pragma unroll
      for (int c = 0; c < 2; c++) {
        bf16x8 vf = *(const bf16x8*)((char*)&V_lds[buf][0] + drow * 128 +
                                     ((c * 64 + g * 16) ^ ((drow & 7) << 4)));
        o_acc[ds_] = __builtin_amdgcn_mfma_f32_16x16x32_bf16(pa[c], vf, o_acc[ds_], 0, 0, 0);
      }
    }
    __builtin_amdgcn_s_setprio(0);
    __syncthreads();
    buf ^= 1;
  }

  #pragma unroll
  for (int r = 0; r < 4; r++) {
    den[r] += __shfl_xor(den[r], 1, 64);
    den[r] += __shfl_xor(den[r], 2, 64);
    den[r] += __shfl_xor(den[r], 4, 64);
    den[r] += __shfl_xor(den[r], 8, 64);
  }

  const int bb = bh >> 4, h = bh & 15;
  #pragma unroll
  for (int ds_ = 0; ds_ < 4; ds_++) {
    #pragma unroll
    for (int r = 0; r < 4; r++) {
      int q = qt * 128 + wid * 16 + g * 4 + r;
      int d = h * 64 + ds_ * 16 + lr;
      attn_out[((size_t)(bb * 1024 + q)) * 1024 + d] = f2bf(o_acc[ds_][r] / den[r]);
    }
  }
}

// ---------------------------------------------------------------------------
extern "C" void kernel_launch(void* const* d_in, const int* in_sizes, int n_in,
                              void* d_out, int out_size, void* d_ws, size_t ws_size,
                              hipStream_t stream) {
  const float* x     = (const float*)d_in[0];
  const float* W_qkv = (const float*)d_in[1];
  const float* b_qkv = (const float*)d_in[2];
  const float* W_o   = (const float*)d_in[3];
  const float* b_o   = (const float*)d_in[4];
  float* out = (float*)d_out;

  unsigned short* ws      = (unsigned short*)d_ws;
  unsigned short* x_bf    = ws;                     //  8388608
  unsigned short* wqkv_t  = x_bf + 8388608;         //  3145728
  unsigned short* wo_t    = wqkv_t + 3145728;       //  1048576
  unsigned short* qkv     = wo_t + 1048576;         // 25165824 (3 x 2^23)
  unsigned short* attn_o  = qkv + 25165824;         //  8388608

  cast_f32_to_bf16<<<2048, 256, 0, stream>>>(x, x_bf, 8388608 / 4);
  transpose_cast<<<dim3(96, 32), 256, 0, stream>>>(W_qkv, wqkv_t, 1024, 3072);
  transpose_cast<<<dim3(32, 32), 256, 0, stream>>>(W_o, wo_t, 1024, 1024);

  // GEMM1: 8192x3072, BM=256 BN=192 -> grid 16x32 = 512 blocks (2 exact rounds)
  gemm_dp<0><<<dim3(16, 32), 512, 0, stream>>>(x_bf, wqkv_t, b_qkv, qkv, nullptr);
  attn_mfma<<<1024, 512, 0, stream>>>(qkv, attn_o);
  // GEMM2: 8192x1024, BM=128 BN=256 -> grid 4x64 = 256 blocks (1 exact round)
  gemm_dp<1><<<dim3(4, 64), 512, 0, stream>>>(attn_o, wo_t, b_o, nullptr, out);
}

// Round 8
// 169.841 us; speedup vs baseline: 1.0053x; 1.0053x over previous
//
#include <hip/hip_runtime.h>

// MHSA fwd MFMA bf16: B=8, N=1024, D=1024, H=16, DK=64. fp32 in/out, bf16 compute.
// Round 8: GEMM1 -> BM=256 BN=256 BK=32, per-wave 128x64 (8m x 4n frags),
// 4-buf LDS (128KB), depth-3 lookahead, vmcnt(8), 4 barriers/tile.
// GEMM2 reverted to round-6 config (BM=128 BN=256 BK=64, 3-buf, vmcnt(6)).
// Attention unchanged from round 3.

typedef __attribute__((ext_vector_type(8))) short bf16x8;
typedef __attribute__((ext_vector_type(4))) float f32x4;

#define GLOAD_LDS16(gp, lp)                                                              \
  __builtin_amdgcn_global_load_lds((const __attribute__((address_space(1))) void*)(gp),  \
                                   (__attribute__((address_space(3))) void*)(lp), 16, 0, 0)

__device__ __forceinline__ unsigned short f2bf(float f) {
  unsigned int u = __float_as_uint(f);
  u += 0x7fffu + ((u >> 16) & 1u);          // RNE
  return (unsigned short)(u >> 16);
}

// ---------------------------------------------------------------------------
__global__ __launch_bounds__(256) void cast_f32_to_bf16(
    const float* __restrict__ in, unsigned short* __restrict__ out, int n4) {
  int stride = gridDim.x * blockDim.x;
  for (int i = blockIdx.x * blockDim.x + threadIdx.x; i < n4; i += stride) {
    float4 v = reinterpret_cast<const float4*>(in)[i];
    ushort4 o;
    o.x = f2bf(v.x); o.y = f2bf(v.y); o.z = f2bf(v.z); o.w = f2bf(v.w);
    reinterpret_cast<ushort4*>(out)[i] = o;
  }
}

// W [R][C] f32 -> Wt [C][R] bf16
__global__ __launch_bounds__(256) void transpose_cast(
    const float* __restrict__ W, unsigned short* __restrict__ Wt, int R, int C) {
  __shared__ float tile[32][33];
  int tx = threadIdx.x & 31, ty = threadIdx.x >> 5;
  int c0 = blockIdx.x * 32, r0 = blockIdx.y * 32;
  #pragma unroll
  for (int i = 0; i < 4; i++) {
    int r = r0 + ty + i * 8;
    tile[ty + i * 8][tx] = W[(size_t)r * C + c0 + tx];
  }
  __syncthreads();
  #pragma unroll
  for (int i = 0; i < 4; i++) {
    int c = c0 + ty + i * 8;
    Wt[(size_t)c * R + r0 + tx] = f2bf(tile[tx][ty + i * 8]);
  }
}

// ---------------------------------------------------------------------------
// GEMM1: qkv = x_bf[8192][1024] @ wqkv_t[3072][1024]^T + bias, scattered.
// BM=256 BN=256 BK=32, 512 thr = 8 waves (2M x 4N), per-wave 128x64 (8x4 frags).
// 4 LDS buffers; tile kt+3 staged during tile kt (A in ph0, B in ph1);
// tile-top vmcnt(8) keeps 2 tiles in flight. 2 phases x 16 MFMA, 4 barriers/tile.
// Q pre-scaled 0.125; V transposed per head to [bh][dk][n].
// ---------------------------------------------------------------------------
__global__ __launch_bounds__(512, 2) void gemm1_k(
    const unsigned short* __restrict__ A, const unsigned short* __restrict__ Bt,
    const float* __restrict__ bias, unsigned short* __restrict__ qkv_out) {
  __shared__ __align__(16) unsigned short As[4][256 * 32];   // 64 KB
  __shared__ __align__(16) unsigned short Bs[4][256 * 32];   // 64 KB

  const int t = threadIdx.x;
  const int lane = t & 63, wid = t >> 6;
  const int lr = lane & 15, g = lane >> 4;
  const int wm = wid >> 2, wn = wid & 3;     // 2M x 4N

  // XCD-aware swizzle (nwg = 384, divisible by 8)
  const int nwg = gridDim.x * gridDim.y;
  const int id = blockIdx.x + gridDim.x * blockIdx.y;
  const int sw = (id & 7) * (nwg >> 3) + (id >> 3);
  const int bx = sw % gridDim.x, by = sw / gridDim.x;
  const int row0 = by * 256, col0 = bx * 256;

  const int srow = t >> 2;                       // 0..127 (64B rows)
  const int sch  = (t & 3) ^ ((srow >> 1) & 3);  // source pre-swizzle chunk

  auto stA = [&](int buf, int kt, int j) {   // j=0..1: rows j*128..j*128+127
    GLOAD_LDS16(A + (size_t)(row0 + j * 128 + srow) * 1024 + kt * 32 + sch * 8,
                (char*)&As[buf][0] + j * 8192 + t * 16);
  };
  auto stB = [&](int buf, int kt, int j) {
    GLOAD_LDS16(Bt + (size_t)(col0 + j * 128 + srow) * 1024 + kt * 32 + sch * 8,
                (char*)&Bs[buf][0] + j * 8192 + t * 16);
  };
  auto rdA = [&](int buf, int m) -> bf16x8 {
    int r = wm * 128 + m * 16 + lr;
    return *(const bf16x8*)((const char*)&As[buf][0] + r * 64 +
                            ((g ^ ((r >> 1) & 3)) * 16));
  };
  auto rdB = [&](int buf, int n) -> bf16x8 {
    int r = wn * 64 + n * 16 + lr;
    return *(const bf16x8*)((const char*)&Bs[buf][0] + r * 64 +
                            ((g ^ ((r >> 1) & 3)) * 16));
  };

  f32x4 acc[8][4] = {};

  // prologue: stage tiles 0..2 (12 loads/wave, oldest-first)
  stA(0, 0, 0); stA(0, 0, 1); stB(0, 0, 0); stB(0, 0, 1);
  stA(1, 1, 0); stA(1, 1, 1); stB(1, 1, 0); stB(1, 1, 1);
  stA(2, 2, 0); stA(2, 2, 1); stB(2, 2, 0); stB(2, 2, 1);

  for (int kt = 0; kt < 32; kt++) {
    const int buf = kt & 3;
    // tile-top counted wait: own tile landed, later tiles stay in flight
    if (kt <= 29)      asm volatile("s_waitcnt vmcnt(8)" ::: "memory");
    else if (kt == 30) asm volatile("s_waitcnt vmcnt(4)" ::: "memory");
    else               asm volatile("s_waitcnt vmcnt(0)" ::: "memory");
    __builtin_amdgcn_s_barrier();

    bf16x8 bfr[4], afr[4];

    // ---- phase 0: m-frags 0..3 (B frags held for both phases) ----
    #pragma unroll
    for (int n = 0; n < 4; n++) bfr[n] = rdB(buf, n);
    #pragma unroll
    for (int m = 0; m < 4; m++) afr[m] = rdA(buf, m);
    if (kt <= 28) { stA((kt + 3) & 3, kt + 3, 0); stA((kt + 3) & 3, kt + 3, 1); }
    __builtin_amdgcn_s_barrier();
    asm volatile("s_waitcnt lgkmcnt(0)" ::: "memory");
    __builtin_amdgcn_sched_barrier(0);
    __builtin_amdgcn_s_setprio(1);
    #pragma unroll
    for (int m = 0; m < 4; m++)
      #pragma unroll
      for (int n = 0; n < 4; n++)
        acc[m][n] = __builtin_amdgcn_mfma_f32_16x16x32_bf16(afr[m], bfr[n], acc[m][n], 0, 0, 0);
    __builtin_amdgcn_s_setprio(0);
    // (no barrier: phase 1 reads the same buffer — no hazard, uniform count)

    // ---- phase 1: m-frags 4..7 ----
    #pragma unroll
    for (int m = 0; m < 4; m++) afr[m] = rdA(buf, 4 + m);
    if (kt <= 28) { stB((kt + 3) & 3, kt + 3, 0); stB((kt + 3) & 3, kt + 3, 1); }
    __builtin_amdgcn_s_barrier();
    asm volatile("s_waitcnt lgkmcnt(0)" ::: "memory");
    __builtin_amdgcn_sched_barrier(0);
    __builtin_amdgcn_s_setprio(1);
    #pragma unroll
    for (int m = 0; m < 4; m++)
      #pragma unroll
      for (int n = 0; n < 4; n++)
        acc[4 + m][n] = __builtin_amdgcn_mfma_f32_16x16x32_bf16(afr[m], bfr[n], acc[4 + m][n], 0, 0, 0);
    __builtin_amdgcn_s_setprio(0);
    __builtin_amdgcn_s_barrier();   // close: buf readers done -> kt+1 may stage into it
  }

  // ---------------- epilogue: qkv scatter ----------------
  const int which = col0 >> 10;   // block-uniform (1024 % 256 == 0)
  #pragma unroll
  for (int m = 0; m < 8; m++) {
    const int row = row0 + wm * 128 + m * 16 + g * 4;
    const int bb = row >> 10, nn = row & 1023;
    #pragma unroll
    for (int n = 0; n < 4; n++) {
      const int col = col0 + wn * 64 + n * 16 + lr;
      const int cc = col & 1023;
      const int h = cc >> 6, dk = cc & 63;
      const float bv = bias[col];
      if (which == 2) {
        ushort4 w;
        w.x = f2bf(acc[m][n][0] + bv);
        w.y = f2bf(acc[m][n][1] + bv);
        w.z = f2bf(acc[m][n][2] + bv);
        w.w = f2bf(acc[m][n][3] + bv);
        size_t idx = ((size_t)2 << 23) + (((size_t)(bb * 16 + h)) << 16) +
                     (size_t)dk * 1024 + nn;
        *(ushort4*)(qkv_out + idx) = w;
      } else {
        const float sc = (which == 0) ? 0.125f : 1.0f;
        #pragma unroll
        for (int r = 0; r < 4; r++) {
          size_t idx = ((size_t)which << 23) +
                       (((size_t)((bb * 16 + h) * 1024 + nn + r)) << 6) + dk;
          qkv_out[idx] = f2bf((acc[m][n][r] + bv) * sc);
        }
      }
    }
  }
}

// ---------------------------------------------------------------------------
// GEMM2 (round-6 config): out = attn_o[8192][1024] @ wo_t[1024][1024]^T + b_o.
// BM=128 BN=256 BK=64, 8 waves (2M x 4N, 64x64/wave), 3-buf LDS, 2-tile
// lookahead, vmcnt(6), 2 phases x 16 MFMA.
// ---------------------------------------------------------------------------
__global__ __launch_bounds__(512) void gemm2_k(
    const unsigned short* __restrict__ A, const unsigned short* __restrict__ Bt,
    const float* __restrict__ bias, float* __restrict__ Cout) {
  __shared__ __align__(16) unsigned short As[3][128 * 64];   // 48 KB
  __shared__ __align__(16) unsigned short Bs[3][256 * 64];   // 96 KB
  const int t = threadIdx.x;
  const int lane = t & 63, wid = t >> 6;
  const int lr = lane & 15, g = lane >> 4;
  const int wm = wid >> 2, wn = wid & 3;

  const int nwg = gridDim.x * gridDim.y;
  const int id = blockIdx.x + gridDim.x * blockIdx.y;
  const int sw = (id & 7) * (nwg >> 3) + (id >> 3);
  const int bx = sw % gridDim.x, by = sw / gridDim.x;
  const int row0 = by * 128, col0 = bx * 256;

  const int srow = t >> 3, sch = t & 7;     // 64 rows of 128B

  auto stA = [&](int buf, int kt, int j) {  // j=0..1
    int row = j * 64 + srow;
    int ch = sch ^ (row & 7);
    GLOAD_LDS16(A + (size_t)(row0 + row) * 1024 + kt * 64 + ch * 8,
                (char*)&As[buf][0] + j * 8192 + t * 16);
  };
  auto stB = [&](int buf, int kt, int j) {  // j=0..3
    int row = j * 64 + srow;
    int ch = sch ^ (row & 7);
    GLOAD_LDS16(Bt + (size_t)(col0 + row) * 1024 + kt * 64 + ch * 8,
                (char*)&Bs[buf][0] + j * 8192 + t * 16);
  };
  auto rdA = [&](int buf, int c, int m) -> bf16x8 {
    int r = wm * 64 + m * 16 + lr;
    return *(const bf16x8*)((const char*)&As[buf][0] + r * 128 +
                            ((c * 64 + g * 16) ^ ((r & 7) << 4)));
  };
  auto rdB = [&](int buf, int c, int n) -> bf16x8 {
    int r = wn * 64 + n * 16 + lr;
    return *(const bf16x8*)((const char*)&Bs[buf][0] + r * 128 +
                            ((c * 64 + g * 16) ^ ((r & 7) << 4)));
  };

  f32x4 acc[4][4] = {};

  stA(0, 0, 0); stA(0, 0, 1);
  stB(0, 0, 0); stB(0, 0, 1); stB(0, 0, 2); stB(0, 0, 3);
  stA(1, 1, 0); stA(1, 1, 1);
  stB(1, 1, 0); stB(1, 1, 1); stB(1, 1, 2); stB(1, 1, 3);
  asm volatile("s_waitcnt vmcnt(6)" ::: "memory");
  __builtin_amdgcn_s_barrier();

  for (int kt = 0; kt < 16; kt++) {
    const int buf = kt % 3;
    const int bufn = (kt + 2) % 3;
    const bool pf = (kt <= 13);
    if (kt > 0) {
      if (kt == 15) asm volatile("s_waitcnt vmcnt(0)" ::: "memory");
      else          asm volatile("s_waitcnt vmcnt(6)" ::: "memory");
      __builtin_amdgcn_s_barrier();
    }

    // ---- phase 0: k-step 0 ----
    bf16x8 a0[4], b0[4];
    #pragma unroll
    for (int m = 0; m < 4; m++) a0[m] = rdA(buf, 0, m);
    #pragma unroll
    for (int n = 0; n < 4; n++) b0[n] = rdB(buf, 0, n);
    if (pf) { stA(bufn, kt + 2, 0); stA(bufn, kt + 2, 1); stB(bufn, kt + 2, 0); }
    __builtin_amdgcn_s_barrier();
    asm volatile("s_waitcnt lgkmcnt(0)" ::: "memory");
    __builtin_amdgcn_sched_barrier(0);
    __builtin_amdgcn_s_setprio(1);
    #pragma unroll
    for (int m = 0; m < 4; m++)
      #pragma unroll
      for (int n = 0; n < 4; n++)
        acc[m][n] = __builtin_amdgcn_mfma_f32_16x16x32_bf16(a0[m], b0[n], acc[m][n], 0, 0, 0);
    __builtin_amdgcn_s_setprio(0);
    __builtin_amdgcn_s_barrier();

    // ---- phase 1: k-step 1 ----
    bf16x8 a1[4], b1[4];
    #pragma unroll
    for (int m = 0; m < 4; m++) a1[m] = rdA(buf, 1, m);
    #pragma unroll
    for (int n = 0; n < 4; n++) b1[n] = rdB(buf, 1, n);
    if (pf) { stB(bufn, kt + 2, 1); stB(bufn, kt + 2, 2); stB(bufn, kt + 2, 3); }
    __builtin_amdgcn_s_barrier();
    asm volatile("s_waitcnt lgkmcnt(0)" ::: "memory");
    __builtin_amdgcn_sched_barrier(0);
    __builtin_amdgcn_s_setprio(1);
    #pragma unroll
    for (int m = 0; m < 4; m++)
      #pragma unroll
      for (int n = 0; n < 4; n++)
        acc[m][n] = __builtin_amdgcn_mfma_f32_16x16x32_bf16(a1[m], b1[n], acc[m][n], 0, 0, 0);
    __builtin_amdgcn_s_setprio(0);
    __builtin_amdgcn_s_barrier();
  }

  #pragma unroll
  for (int m = 0; m < 4; m++) {
    #pragma unroll
    for (int n = 0; n < 4; n++) {
      int col = col0 + wn * 64 + n * 16 + lr;
      #pragma unroll
      for (int r = 0; r < 4; r++) {
        int row = row0 + wm * 64 + m * 16 + g * 4 + r;
        Cout[(size_t)row * 1024 + col] = acc[m][n][r] + bias[col];
      }
    }
  }
}

// ---------------------------------------------------------------------------
// Attention (unchanged): 8 waves, QBLK=128, KVBLK=64, dbuf prefetch,
// V pre-transposed by GEMM1, setprio, XCD swizzle.
// ---------------------------------------------------------------------------
__global__ __launch_bounds__(512) void attn_mfma(
    const unsigned short* __restrict__ qkv, unsigned short* __restrict__ attn_out) {
  __shared__ __align__(16) unsigned short K_lds[2][64 * 64];   // [k][d] swz
  __shared__ __align__(16) unsigned short V_lds[2][64 * 64];   // [d][k] swz
  __shared__ __align__(16) unsigned short P_lds[128 * 64];     // [q][k] swz

  const int bid = ((blockIdx.x & 7) << 7) + (blockIdx.x >> 3);
  const int bh = bid >> 3, qt = bid & 7;
  const unsigned short* Qp = qkv + ((size_t)bh << 16);
  const unsigned short* Kp = qkv + (1u << 23) + ((size_t)bh << 16);
  const unsigned short* Vt = qkv + (2u << 23) + ((size_t)bh << 16);  // [dk][n]

  const int t = threadIdx.x;
  const int lane = t & 63, wid = t >> 6;
  const int lr = lane & 15, g = lane >> 4;

  bf16x8 qf[2];
  {
    int qrow = qt * 128 + wid * 16 + lr;
    qf[0] = *(const bf16x8*)(Qp + (size_t)qrow * 64 + g * 8);
    qf[1] = *(const bf16x8*)(Qp + (size_t)qrow * 64 + 32 + g * 8);
  }

  const int srow = t >> 3;
  const int sch  = (t & 7) ^ (srow & 7);
  const int so   = t * 16;

  auto stage = [&](int buf, int kt) {
    GLOAD_LDS16(Kp + (size_t)(kt * 64 + srow) * 64 + sch * 8, (char*)&K_lds[buf][0] + so);
    GLOAD_LDS16(Vt + (size_t)srow * 1024 + kt * 64 + sch * 8, (char*)&V_lds[buf][0] + so);
  };

  f32x4 o_acc[4] = {};
  float den[4] = {0.f, 0.f, 0.f, 0.f};

  stage(0, 0);
  __syncthreads();
  int buf = 0;
  for (int kt = 0; kt < 16; kt++) {
    if (kt + 1 < 16) stage(buf ^ 1, kt + 1);

    f32x4 s4[4] = {};
    __builtin_amdgcn_s_setprio(1);
    #pragma unroll
    for (int ks = 0; ks < 4; ks++) {
      int krow = ks * 16 + lr;
      #pragma unroll
      for (int c = 0; c < 2; c++) {
        bf16x8 kf = *(const bf16x8*)((char*)&K_lds[buf][0] + krow * 128 +
                                     ((c * 64 + g * 16) ^ ((krow & 7) << 4)));
        s4[ks] = __builtin_amdgcn_mfma_f32_16x16x32_bf16(qf[c], kf, s4[ks], 0, 0, 0);
      }
    }
    __builtin_amdgcn_s_setprio(0);

    #pragma unroll
    for (int ks = 0; ks < 4; ks++) {
      #pragma unroll
      for (int r = 0; r < 4; r++) {
        float e = __expf(s4[ks][r]);
        den[r] += e;
        int q = wid * 16 + g * 4 + r;
        *(unsigned short*)((char*)P_lds + q * 128 +
                           (((ks * 16 + lr) * 2) ^ ((q & 7) << 4))) = f2bf(e);
      }
    }

    bf16x8 pa[2];
    {
      int q = wid * 16 + lr;
      #pragma unroll
      for (int c = 0; c < 2; c++)
        pa[c] = *(const bf16x8*)((char*)P_lds + q * 128 +
                                 ((c * 64 + g * 16) ^ ((q & 7) << 4)));
    }
    __builtin_amdgcn_s_setprio(1);
    #pragma unroll
    for (int ds_ = 0; ds_ < 4; ds_++) {
      int drow = ds_ * 16 + lr;
      #pragma unroll
      for (int c = 0; c < 2; c++) {
        bf16x8 vf = *(const bf16x8*)((char*)&V_lds[buf][0] + drow * 128 +
                                     ((c * 64 + g * 16) ^ ((drow & 7) << 4)));
        o_acc[ds_] = __builtin_amdgcn_mfma_f32_16x16x32_bf16(pa[c], vf, o_acc[ds_], 0, 0, 0);
      }
    }
    __builtin_amdgcn_s_setprio(0);
    __syncthreads();
    buf ^= 1;
  }

  #pragma unroll
  for (int r = 0; r < 4; r++) {
    den[r] += __shfl_xor(den[r], 1, 64);
    den[r] += __shfl_xor(den[r], 2, 64);
    den[r] += __shfl_xor(den[r], 4, 64);
    den[r] += __shfl_xor(den[r], 8, 64);
  }

  const int bb = bh >> 4, h = bh & 15;
  #pragma unroll
  for (int ds_ = 0; ds_ < 4; ds_++) {
    #pragma unroll
    for (int r = 0; r < 4; r++) {
      int q = qt * 128 + wid * 16 + g * 4 + r;
      int d = h * 64 + ds_ * 16 + lr;
      attn_out[((size_t)(bb * 1024 + q)) * 1024 + d] = f2bf(o_acc[ds_][r] / den[r]);
    }
  }
}

// ---------------------------------------------------------------------------
extern "C" void kernel_launch(void* const* d_in, const int* in_sizes, int n_in,
                              void* d_out, int out_size, void* d_ws, size_t ws_size,
                              hipStream_t stream) {
  const float* x     = (const float*)d_in[0];
  const float* W_qkv = (const float*)d_in[1];
  const float* b_qkv = (const float*)d_in[2];
  const float* W_o   = (const float*)d_in[3];
  const float* b_o   = (const float*)d_in[4];
  float* out = (float*)d_out;

  unsigned short* ws      = (unsigned short*)d_ws;
  unsigned short* x_bf    = ws;                     //  8388608
  unsigned short* wqkv_t  = x_bf + 8388608;         //  3145728
  unsigned short* wo_t    = wqkv_t + 3145728;       //  1048576
  unsigned short* qkv     = wo_t + 1048576;         // 25165824 (3 x 2^23)
  unsigned short* attn_o  = qkv + 25165824;         //  8388608

  cast_f32_to_bf16<<<2048, 256, 0, stream>>>(x, x_bf, 8388608 / 4);
  transpose_cast<<<dim3(96, 32), 256, 0, stream>>>(W_qkv, wqkv_t, 1024, 3072);
  transpose_cast<<<dim3(32, 32), 256, 0, stream>>>(W_o, wo_t, 1024, 1024);

  // GEMM1: 8192x3072, BM=256 BN=256 -> grid 12x32 = 384 blocks
  gemm1_k<<<dim3(12, 32), 512, 0, stream>>>(x_bf, wqkv_t, b_qkv, qkv);
  attn_mfma<<<1024, 512, 0, stream>>>(qkv, attn_o);
  // GEMM2: 8192x1024, BM=128 BN=256 -> grid 4x64 = 256 blocks (1 exact round)
  gemm2_k<<<dim3(4, 64), 512, 0, stream>>>(attn_o, wo_t, b_o, out);
}

// Round 9
// 162.485 us; speedup vs baseline: 1.0508x; 1.0453x over previous
//
#include <hip/hip_runtime.h>

// MHSA fwd MFMA bf16: B=8, N=1024, D=1024, H=16, DK=64. fp32 in/out, bf16 compute.
// Round 9: GEMM1 reverted to round-6 config (128x256 BK=64, 3-buf, vmcnt(6)) —
// best measured (71.5us). Attention upgraded: 3-buf K/V, 2-tile lookahead,
// counted vmcnt(2) + raw barrier per tile (no more prefetch drain).

typedef __attribute__((ext_vector_type(8))) short bf16x8;
typedef __attribute__((ext_vector_type(4))) float f32x4;

#define GLOAD_LDS16(gp, lp)                                                              \
  __builtin_amdgcn_global_load_lds((const __attribute__((address_space(1))) void*)(gp),  \
                                   (__attribute__((address_space(3))) void*)(lp), 16, 0, 0)

__device__ __forceinline__ unsigned short f2bf(float f) {
  unsigned int u = __float_as_uint(f);
  u += 0x7fffu + ((u >> 16) & 1u);          // RNE
  return (unsigned short)(u >> 16);
}

// ---------------------------------------------------------------------------
__global__ __launch_bounds__(256) void cast_f32_to_bf16(
    const float* __restrict__ in, unsigned short* __restrict__ out, int n4) {
  int stride = gridDim.x * blockDim.x;
  for (int i = blockIdx.x * blockDim.x + threadIdx.x; i < n4; i += stride) {
    float4 v = reinterpret_cast<const float4*>(in)[i];
    ushort4 o;
    o.x = f2bf(v.x); o.y = f2bf(v.y); o.z = f2bf(v.z); o.w = f2bf(v.w);
    reinterpret_cast<ushort4*>(out)[i] = o;
  }
}

// W [R][C] f32 -> Wt [C][R] bf16
__global__ __launch_bounds__(256) void transpose_cast(
    const float* __restrict__ W, unsigned short* __restrict__ Wt, int R, int C) {
  __shared__ float tile[32][33];
  int tx = threadIdx.x & 31, ty = threadIdx.x >> 5;
  int c0 = blockIdx.x * 32, r0 = blockIdx.y * 32;
  #pragma unroll
  for (int i = 0; i < 4; i++) {
    int r = r0 + ty + i * 8;
    tile[ty + i * 8][tx] = W[(size_t)r * C + c0 + tx];
  }
  __syncthreads();
  #pragma unroll
  for (int i = 0; i < 4; i++) {
    int c = c0 + ty + i * 8;
    Wt[(size_t)c * R + r0 + tx] = f2bf(tile[tx][ty + i * 8]);
  }
}

// ---------------------------------------------------------------------------
// GEMM (round-6 proven config): 128x256, BK=64, 512 thr (8 waves = 2M x 4N;
// 64x64 per wave). K=1024 -> 16 K-tiles. 3-buf LDS; tile kt+2 staged during
// tile kt (3+3 loads across 2 phases); tile-top vmcnt(6). 2 phases x 16 MFMA.
// MODE 0: qkv scatter (Q pre-scaled 0.125, V transposed per head). MODE 1: f32.
// ---------------------------------------------------------------------------
template <int MODE>
__global__ __launch_bounds__(512) void gemm256(
    const unsigned short* __restrict__ A, const unsigned short* __restrict__ Bt,
    const float* __restrict__ bias, unsigned short* __restrict__ qkv_out,
    float* __restrict__ Cout) {
  __shared__ __align__(16) unsigned short As[3][128 * 64];   // 48 KB
  __shared__ __align__(16) unsigned short Bs[3][256 * 64];   // 96 KB
  const int t = threadIdx.x;
  const int lane = t & 63, wid = t >> 6;
  const int lr = lane & 15, g = lane >> 4;
  const int wm = wid >> 2, wn = wid & 3;

  const int nwg = gridDim.x * gridDim.y;
  const int id = blockIdx.x + gridDim.x * blockIdx.y;
  const int sw = (id & 7) * (nwg >> 3) + (id >> 3);
  const int bx = sw % gridDim.x, by = sw / gridDim.x;
  const int row0 = by * 128, col0 = bx * 256;

  const int srow = t >> 3, sch = t & 7;     // 64 rows of 128B

  auto stA = [&](int buf, int kt, int j) {  // j=0..1
    int row = j * 64 + srow;
    int ch = sch ^ (row & 7);
    GLOAD_LDS16(A + (size_t)(row0 + row) * 1024 + kt * 64 + ch * 8,
                (char*)&As[buf][0] + j * 8192 + t * 16);
  };
  auto stB = [&](int buf, int kt, int j) {  // j=0..3
    int row = j * 64 + srow;
    int ch = sch ^ (row & 7);
    GLOAD_LDS16(Bt + (size_t)(col0 + row) * 1024 + kt * 64 + ch * 8,
                (char*)&Bs[buf][0] + j * 8192 + t * 16);
  };
  auto rdA = [&](int buf, int c, int m) -> bf16x8 {
    int r = wm * 64 + m * 16 + lr;
    return *(const bf16x8*)((const char*)&As[buf][0] + r * 128 +
                            ((c * 64 + g * 16) ^ ((r & 7) << 4)));
  };
  auto rdB = [&](int buf, int c, int n) -> bf16x8 {
    int r = wn * 64 + n * 16 + lr;
    return *(const bf16x8*)((const char*)&Bs[buf][0] + r * 128 +
                            ((c * 64 + g * 16) ^ ((r & 7) << 4)));
  };

  f32x4 acc[4][4] = {};

  stA(0, 0, 0); stA(0, 0, 1);
  stB(0, 0, 0); stB(0, 0, 1); stB(0, 0, 2); stB(0, 0, 3);
  stA(1, 1, 0); stA(1, 1, 1);
  stB(1, 1, 0); stB(1, 1, 1); stB(1, 1, 2); stB(1, 1, 3);
  asm volatile("s_waitcnt vmcnt(6)" ::: "memory");
  __builtin_amdgcn_s_barrier();

  for (int kt = 0; kt < 16; kt++) {
    const int buf = kt % 3;
    const int bufn = (kt + 2) % 3;
    const bool pf = (kt <= 13);
    if (kt > 0) {
      if (kt == 15) asm volatile("s_waitcnt vmcnt(0)" ::: "memory");
      else          asm volatile("s_waitcnt vmcnt(6)" ::: "memory");
      __builtin_amdgcn_s_barrier();
    }

    // ---- phase 0: k-step 0 ----
    bf16x8 a0[4], b0[4];
    #pragma unroll
    for (int m = 0; m < 4; m++) a0[m] = rdA(buf, 0, m);
    #pragma unroll
    for (int n = 0; n < 4; n++) b0[n] = rdB(buf, 0, n);
    if (pf) { stA(bufn, kt + 2, 0); stA(bufn, kt + 2, 1); stB(bufn, kt + 2, 0); }
    __builtin_amdgcn_s_barrier();
    asm volatile("s_waitcnt lgkmcnt(0)" ::: "memory");
    __builtin_amdgcn_sched_barrier(0);
    __builtin_amdgcn_s_setprio(1);
    #pragma unroll
    for (int m = 0; m < 4; m++)
      #pragma unroll
      for (int n = 0; n < 4; n++)
        acc[m][n] = __builtin_amdgcn_mfma_f32_16x16x32_bf16(a0[m], b0[n], acc[m][n], 0, 0, 0);
    __builtin_amdgcn_s_setprio(0);
    __builtin_amdgcn_s_barrier();

    // ---- phase 1: k-step 1 ----
    bf16x8 a1[4], b1[4];
    #pragma unroll
    for (int m = 0; m < 4; m++) a1[m] = rdA(buf, 1, m);
    #pragma unroll
    for (int n = 0; n < 4; n++) b1[n] = rdB(buf, 1, n);
    if (pf) { stB(bufn, kt + 2, 1); stB(bufn, kt + 2, 2); stB(bufn, kt + 2, 3); }
    __builtin_amdgcn_s_barrier();
    asm volatile("s_waitcnt lgkmcnt(0)" ::: "memory");
    __builtin_amdgcn_sched_barrier(0);
    __builtin_amdgcn_s_setprio(1);
    #pragma unroll
    for (int m = 0; m < 4; m++)
      #pragma unroll
      for (int n = 0; n < 4; n++)
        acc[m][n] = __builtin_amdgcn_mfma_f32_16x16x32_bf16(a1[m], b1[n], acc[m][n], 0, 0, 0);
    __builtin_amdgcn_s_setprio(0);
    __builtin_amdgcn_s_barrier();
  }

  // ---------------- epilogue ----------------
  if (MODE == 0) {
    const int which = col0 >> 10;   // block-uniform (1024 % 256 == 0)
    if (which == 2) {
      #pragma unroll
      for (int m = 0; m < 4; m++) {
        int row = row0 + wm * 64 + m * 16 + g * 4;
        int bb = row >> 10, nn = row & 1023;
        #pragma unroll
        for (int n = 0; n < 4; n++) {
          int col = col0 + wn * 64 + n * 16 + lr;
          int cc = col & 1023;
          int h = cc >> 6, dk = cc & 63;
          float bv = bias[col];
          ushort4 w;
          w.x = f2bf(acc[m][n][0] + bv);
          w.y = f2bf(acc[m][n][1] + bv);
          w.z = f2bf(acc[m][n][2] + bv);
          w.w = f2bf(acc[m][n][3] + bv);
          size_t idx = ((size_t)2 << 23) + (((size_t)(bb * 16 + h)) << 16) +
                       (size_t)dk * 1024 + nn;
          *(ushort4*)(qkv_out + idx) = w;
        }
      }
    } else {
      #pragma unroll
      for (int m = 0; m < 4; m++) {
        #pragma unroll
        for (int n = 0; n < 4; n++) {
          int col = col0 + wn * 64 + n * 16 + lr;
          int cc = col & 1023;
          int h = cc >> 6, dk = cc & 63;
          #pragma unroll
          for (int r = 0; r < 4; r++) {
            int row = row0 + wm * 64 + m * 16 + g * 4 + r;
            int bb = row >> 10, nn = row & 1023;
            float v = acc[m][n][r] + bias[col];
            if (which == 0) v *= 0.125f;   // fold 1/sqrt(dk) into Q
            size_t idx = ((size_t)which << 23) +
                         (((size_t)((bb * 16 + h) * 1024 + nn)) << 6) + dk;
            qkv_out[idx] = f2bf(v);
          }
        }
      }
    }
  } else {
    #pragma unroll
    for (int m = 0; m < 4; m++) {
      #pragma unroll
      for (int n = 0; n < 4; n++) {
        int col = col0 + wn * 64 + n * 16 + lr;
        #pragma unroll
        for (int r = 0; r < 4; r++) {
          int row = row0 + wm * 64 + m * 16 + g * 4 + r;
          Cout[(size_t)row * 1024 + col] = acc[m][n][r] + bias[col];
        }
      }
    }
  }
}

// ---------------------------------------------------------------------------
// Attention v3: 8 waves, QBLK=128, KVBLK=64. 3-buf K/V, stage(kt+2) at tile
// top, end-of-tile counted vmcnt(2) + raw barrier (loads get 2 tile-times to
// land; prefetch never drained). QK^T -> exp -> P_lds (wave-local) -> PV.
// V pre-transposed by GEMM1; setprio; XCD swizzle. No max-subtract.
// ---------------------------------------------------------------------------
__global__ __launch_bounds__(512) void attn_mfma(
    const unsigned short* __restrict__ qkv, unsigned short* __restrict__ attn_out) {
  __shared__ __align__(16) unsigned short K_lds[3][64 * 64];   // [k][d] swz, 24 KB
  __shared__ __align__(16) unsigned short V_lds[3][64 * 64];   // [d][k] swz, 24 KB
  __shared__ __align__(16) unsigned short P_lds[128 * 64];     // [q][k] swz, 16 KB

  const int bid = ((blockIdx.x & 7) << 7) + (blockIdx.x >> 3);
  const int bh = bid >> 3, qt = bid & 7;
  const unsigned short* Qp = qkv + ((size_t)bh << 16);
  const unsigned short* Kp = qkv + (1u << 23) + ((size_t)bh << 16);
  const unsigned short* Vt = qkv + (2u << 23) + ((size_t)bh << 16);  // [dk][n]

  const int t = threadIdx.x;
  const int lane = t & 63, wid = t >> 6;
  const int lr = lane & 15, g = lane >> 4;

  bf16x8 qf[2];
  {
    int qrow = qt * 128 + wid * 16 + lr;
    qf[0] = *(const bf16x8*)(Qp + (size_t)qrow * 64 + g * 8);
    qf[1] = *(const bf16x8*)(Qp + (size_t)qrow * 64 + 32 + g * 8);
  }

  const int srow = t >> 3;
  const int sch  = (t & 7) ^ (srow & 7);
  const int so   = t * 16;

  auto stage = [&](int buf, int kt) {
    GLOAD_LDS16(Kp + (size_t)(kt * 64 + srow) * 64 + sch * 8, (char*)&K_lds[buf][0] + so);
    GLOAD_LDS16(Vt + (size_t)srow * 1024 + kt * 64 + sch * 8, (char*)&V_lds[buf][0] + so);
  };

  f32x4 o_acc[4] = {};
  float den[4] = {0.f, 0.f, 0.f, 0.f};

  // prologue: 2 tiles in flight, wait only for tile 0
  stage(0, 0); stage(1, 1);
  asm volatile("s_waitcnt vmcnt(2)" ::: "memory");
  __builtin_amdgcn_s_barrier();

  for (int kt = 0; kt < 16; kt++) {
    const int buf = kt % 3;
    if (kt + 2 < 16) stage((kt + 2) % 3, kt + 2);

    f32x4 s4[4] = {};
    __builtin_amdgcn_s_setprio(1);
    #pragma unroll
    for (int ks = 0; ks < 4; ks++) {
      int krow = ks * 16 + lr;
      #pragma unroll
      for (int c = 0; c < 2; c++) {
        bf16x8 kf = *(const bf16x8*)((char*)&K_lds[buf][0] + krow * 128 +
                                     ((c * 64 + g * 16) ^ ((krow & 7) << 4)));
        s4[ks] = __builtin_amdgcn_mfma_f32_16x16x32_bf16(qf[c], kf, s4[ks], 0, 0, 0);
      }
    }
    __builtin_amdgcn_s_setprio(0);

    #pragma unroll
    for (int ks = 0; ks < 4; ks++) {
      #pragma unroll
      for (int r = 0; r < 4; r++) {
        float e = __expf(s4[ks][r]);
        den[r] += e;
        int q = wid * 16 + g * 4 + r;
        *(unsigned short*)((char*)P_lds + q * 128 +
                           (((ks * 16 + lr) * 2) ^ ((q & 7) << 4))) = f2bf(e);
      }
    }

    bf16x8 pa[2];
    {
      int q = wid * 16 + lr;
      #pragma unroll
      for (int c = 0; c < 2; c++)
        pa[c] = *(const bf16x8*)((char*)P_lds + q * 128 +
                                 ((c * 64 + g * 16) ^ ((q & 7) << 4)));
    }
    __builtin_amdgcn_s_setprio(1);
    #pragma unroll
    for (int ds_ = 0; ds_ < 4; ds_++) {
      int drow = ds_ * 16 + lr;
      #pragma unroll
      for (int c = 0; c < 2; c++) {
        bf16x8 vf = *(const bf16x8*)((char*)&V_lds[buf][0] + drow * 128 +
                                     ((c * 64 + g * 16) ^ ((drow & 7) << 4)));
        o_acc[ds_] = __builtin_amdgcn_mfma_f32_16x16x32_bf16(pa[c], vf, o_acc[ds_], 0, 0, 0);
      }
    }
    __builtin_amdgcn_s_setprio(0);

    // end of tile: kt+1's loads landed (kt+2's may stay in flight); no drain.
    if (kt <= 13)      asm volatile("s_waitcnt vmcnt(2)" ::: "memory");
    else if (kt == 14) asm volatile("s_waitcnt vmcnt(0)" ::: "memory");
    if (kt < 15) __builtin_amdgcn_s_barrier();
  }

  #pragma unroll
  for (int r = 0; r < 4; r++) {
    den[r] += __shfl_xor(den[r], 1, 64);
    den[r] += __shfl_xor(den[r], 2, 64);
    den[r] += __shfl_xor(den[r], 4, 64);
    den[r] += __shfl_xor(den[r], 8, 64);
  }

  const int bb = bh >> 4, h = bh & 15;
  #pragma unroll
  for (int ds_ = 0; ds_ < 4; ds_++) {
    #pragma unroll
    for (int r = 0; r < 4; r++) {
      int q = qt * 128 + wid * 16 + g * 4 + r;
      int d = h * 64 + ds_ * 16 + lr;
      attn_out[((size_t)(bb * 1024 + q)) * 1024 + d] = f2bf(o_acc[ds_][r] / den[r]);
    }
  }
}

// ---------------------------------------------------------------------------
extern "C" void kernel_launch(void* const* d_in, const int* in_sizes, int n_in,
                              void* d_out, int out_size, void* d_ws, size_t ws_size,
                              hipStream_t stream) {
  const float* x     = (const float*)d_in[0];
  const float* W_qkv = (const float*)d_in[1];
  const float* b_qkv = (const float*)d_in[2];
  const float* W_o   = (const float*)d_in[3];
  const float* b_o   = (const float*)d_in[4];
  float* out = (float*)d_out;

  unsigned short* ws      = (unsigned short*)d_ws;
  unsigned short* x_bf    = ws;                     //  8388608
  unsigned short* wqkv_t  = x_bf + 8388608;         //  3145728
  unsigned short* wo_t    = wqkv_t + 3145728;       //  1048576
  unsigned short* qkv     = wo_t + 1048576;         // 25165824 (3 x 2^23)
  unsigned short* attn_o  = qkv + 25165824;         //  8388608

  cast_f32_to_bf16<<<2048, 256, 0, stream>>>(x, x_bf, 8388608 / 4);
  transpose_cast<<<dim3(96, 32), 256, 0, stream>>>(W_qkv, wqkv_t, 1024, 3072);
  transpose_cast<<<dim3(32, 32), 256, 0, stream>>>(W_o, wo_t, 1024, 1024);

  gemm256<0><<<dim3(12, 64), 512, 0, stream>>>(x_bf, wqkv_t, b_qkv, qkv, nullptr);
  attn_mfma<<<1024, 512, 0, stream>>>(qkv, attn_o);
  gemm256<1><<<dim3(4, 64), 512, 0, stream>>>(attn_o, wo_t, b_o, nullptr, out);
}